// Round 8
// baseline (189.197 us; speedup 1.0000x reference)
//
#include <hip/hip_runtime.h>
#include <hip/hip_bf16.h>
#include <math.h>

// Problem constants (fixed by setup_inputs)
#define BATCH 8
#define SEQ   4096
#define DIM   512        // D
#define FDIM  4          // F
#define M_TOTAL (BATCH*SEQ)   // 32768 positions
#define K_TOTAL (2*DIM)       // 1024 (cat = [ctx; q])
#define N_TOTAL DIM           // 512

#define MB 32                          // positions per block
#define FUSED_BLOCKS (M_TOTAL/MB)      // 1024
#define WCONV_BLOCKS ((K_TOTAL/64)*(N_TOTAL/64))  // 128 tiles

typedef __bf16 bf16x8 __attribute__((ext_vector_type(8)));
typedef float  f32x4  __attribute__((ext_vector_type(4)));

__device__ __forceinline__ float dot4(float4 a, float4 b) {
    return a.x*b.x + a.y*b.y + a.z*b.z + a.w*b.w;
}

__device__ __forceinline__ void store_bf4(__hip_bfloat16* dst, float4 v) {
    __hip_bfloat16 t[4];
    t[0] = __float2bfloat16(v.x); t[1] = __float2bfloat16(v.y);
    t[2] = __float2bfloat16(v.z); t[3] = __float2bfloat16(v.w);
    *reinterpret_cast<uint2*>(dst) = *reinterpret_cast<const uint2*>(t);
}

__device__ __forceinline__ float fast_tanh(float x) {
    // tanh(x) = 1 - 2/(e^{2x}+1); saturates correctly for |x| large
    float e = __expf(2.f * x);
    return 1.f - 2.f * __builtin_amdgcn_rcpf(e + 1.f);
}

// ---------------------------------------------------------------------------
// Kernel 1: W_out [1024,512] f32 -> Wt [512,1024] bf16 (transpose+convert).
// Stream-ordered BEFORE the fused kernel so Wt is ready.
// ---------------------------------------------------------------------------
__global__ __launch_bounds__(256)
void wconv(const float* __restrict__ W, __hip_bfloat16* __restrict__ Wt)
{
    __shared__ float ws[64][65];
    const int tid = threadIdx.x;
    const int t  = blockIdx.x;
    const int k0 = (t & 15) * 64;     // row tile in W (K dim)
    const int n0 = (t >> 4) * 64;     // col tile in W (N dim)
    #pragma unroll
    for (int i = 0; i < 16; ++i) {
        int e = i * 256 + tid;
        int r = e >> 6, c = e & 63;
        ws[r][c] = W[(size_t)(k0 + r) * N_TOTAL + n0 + c];
    }
    __syncthreads();
    #pragma unroll
    for (int i = 0; i < 16; ++i) {
        int e = i * 256 + tid;
        int nr = e >> 6, kc = e & 63;
        Wt[(size_t)(n0 + nr) * K_TOTAL + k0 + kc] = __float2bfloat16(ws[kc][nr]);
    }
}

// ---------------------------------------------------------------------------
// cat LDS layout: [MB rows][1024 K] bf16, rows of 2048 B = 128 chunks of 16 B.
// Chunk ck holds k = ck*8..ck*8+7 at physical chunk (ck ^ (row&7)) — XOR
// swizzle so a 16-lane MFMA A-frag read (16 rows, same ck) spreads across
// all 32 banks (2-way aliasing = free).
// ---------------------------------------------------------------------------
__device__ __forceinline__ void cat_store4(__hip_bfloat16* catL, int row, int k, float4 v) {
    int ck   = k >> 3;
    int phys = ck ^ (row & 7);
    char* dst = (char*)catL + row * 2048 + (phys << 4) + ((k & 7) << 1);
    store_bf4((__hip_bfloat16*)dst, v);
}

// ---------------------------------------------------------------------------
// Kernel 2 (fused): per block of MB=32 positions:
//   phase 1: wave-per-position attention -> cat=[ctx;q] bf16 in LDS + gate
//   phase 2: GEMM [32,1024]x[1024,512] via MFMA; A from LDS, B from L2-hot Wt
//   epilogue: out = tanh(acc)*gate + q   (q residual from LDS cat)
// LDS 64.1 KiB -> 2 blocks/CU: one block's attention overlaps the other's GEMM.
// ---------------------------------------------------------------------------
__global__ __launch_bounds__(256, 2)
void fused_kernel(const float* __restrict__ inputs,
                  const float* __restrict__ values,
                  const __hip_bfloat16* __restrict__ Bt,   // Wt [512][1024]
                  const float* __restrict__ w_score,
                  const float* __restrict__ b_score,
                  const int*   __restrict__ n_ptr,
                  float* __restrict__ out)
{
    __shared__ __align__(16) __hip_bfloat16 catL[MB * K_TOTAL];  // 64 KiB
    __shared__ float gateL[MB];

    const int tid  = threadIdx.x;
    const int lane = tid & 63;
    const int wv   = tid >> 6;          // 4 waves
    const int bp   = blockIdx.x * MB;   // block's first position
    const int nv   = *n_ptr;

    // ---------------- phase 1: attention (wave-per-position) ----------------
    const float4* wg = (const float4*)w_score;
    #pragma unroll 2
    for (int it = 0; it < MB / 4; ++it) {
        const int p = wv * (MB / 4) + it;            // local row 0..31
        const float4* qg = (const float4*)(inputs + (size_t)(bp + p) * DIM);
        float4 qa = qg[lane], qb = qg[lane + 64];

        const float4* vg = (const float4*)(values + (size_t)(bp + p) * (FDIM*DIM));
        float4 ma[4], mb[4];
        float s[4];
        #pragma unroll
        for (int f = 0; f < 4; ++f) {
            ma[f] = vg[f * 128 + lane];
            mb[f] = vg[f * 128 + lane + 64];
            s[f] = dot4(qa, ma[f]) + dot4(qb, mb[f]);
        }
        float g = dot4(qa, wg[lane]) + dot4(qb, wg[lane + 64]);

        #pragma unroll
        for (int off = 1; off < 64; off <<= 1) {
            s[0] += __shfl_xor(s[0], off, 64);
            s[1] += __shfl_xor(s[1], off, 64);
            s[2] += __shfl_xor(s[2], off, 64);
            s[3] += __shfl_xor(s[3], off, 64);
            g    += __shfl_xor(g,    off, 64);
        }

        #pragma unroll
        for (int f = 0; f < 4; ++f) if (f >= nv) s[f] = -1e9f;
        float mx = fmaxf(fmaxf(s[0], s[1]), fmaxf(s[2], s[3]));
        float e0 = __expf(s[0] - mx), e1 = __expf(s[1] - mx);
        float e2 = __expf(s[2] - mx), e3 = __expf(s[3] - mx);
        float inv = __builtin_amdgcn_rcpf(e0 + e1 + e2 + e3);
        float a0 = e0*inv, a1 = e1*inv, a2 = e2*inv, a3 = e3*inv;

        float4 ca, cb;
        ca.x = a0*ma[0].x + a1*ma[1].x + a2*ma[2].x + a3*ma[3].x;
        ca.y = a0*ma[0].y + a1*ma[1].y + a2*ma[2].y + a3*ma[3].y;
        ca.z = a0*ma[0].z + a1*ma[1].z + a2*ma[2].z + a3*ma[3].z;
        ca.w = a0*ma[0].w + a1*ma[1].w + a2*ma[2].w + a3*ma[3].w;
        cb.x = a0*mb[0].x + a1*mb[1].x + a2*mb[2].x + a3*mb[3].x;
        cb.y = a0*mb[0].y + a1*mb[1].y + a2*mb[2].y + a3*mb[3].y;
        cb.z = a0*mb[0].z + a1*mb[1].z + a2*mb[2].z + a3*mb[3].z;
        cb.w = a0*mb[0].w + a1*mb[1].w + a2*mb[2].w + a3*mb[3].w;

        // cat row p: ctx at k=[0,512), q at k=[512,1024)
        cat_store4(catL, p,         lane * 4, ca);
        cat_store4(catL, p, 256  +  lane * 4, cb);
        cat_store4(catL, p, 512  +  lane * 4, qa);
        cat_store4(catL, p, 768  +  lane * 4, qb);

        if (lane == 0) {
            float t = g + b_score[0];
            gateL[p] = __builtin_amdgcn_rcpf(1.f + __expf(-t));
        }
    }
    __syncthreads();

    // ---------------- phase 2: GEMM (no barriers, A read-only in LDS) -------
    const int la = lane & 15;
    const int lb = lane >> 4;
    const int nw = wv * 128;            // wave's N-chunk

    f32x4 acc[2][8] = {};

    // one step = (kt, kk): K range kt*64 + kk*32 .. +32
#define LOADSTEP(af, bf, kt, kk) do {                                         \
        int ck0 = (kt) * 8 + (kk) * 4 + lb;                                   \
        _Pragma("unroll")                                                     \
        for (int m = 0; m < 2; ++m) {                                         \
            int row = m * 16 + la;                                            \
            af[m] = *reinterpret_cast<const bf16x8*>(                         \
                (const char*)catL + row * 2048 + ((ck0 ^ (row & 7)) << 4));   \
        }                                                                     \
        _Pragma("unroll")                                                     \
        for (int j = 0; j < 8; ++j) {                                         \
            int nrow = nw + j * 16 + la;                                      \
            bf[j] = *reinterpret_cast<const bf16x8*>(                         \
                Bt + (size_t)nrow * K_TOTAL + (kt) * 64 + (kk) * 32 + lb * 8);\
        }                                                                     \
    } while (0)

#define MFMASTEP(af, bf) do {                                                 \
        _Pragma("unroll")                                                     \
        for (int m = 0; m < 2; ++m)                                           \
            _Pragma("unroll")                                                 \
            for (int j = 0; j < 8; ++j)                                       \
                acc[m][j] = __builtin_amdgcn_mfma_f32_16x16x32_bf16(          \
                    af[m], bf[j], acc[m][j], 0, 0, 0);                        \
    } while (0)

    bf16x8 aA[2], bA[8], aB[2], bB[8];
    LOADSTEP(aA, bA, 0, 0);
    #pragma unroll
    for (int s = 0; s < 31; ++s) {
        const int ns = s + 1, nkt = ns >> 1, nkk = ns & 1;
        if ((s & 1) == 0) { LOADSTEP(aB, bB, nkt, nkk); MFMASTEP(aA, bA); }
        else              { LOADSTEP(aA, bA, nkt, nkk); MFMASTEP(aB, bB); }
    }
    MFMASTEP(aB, bB);

    // ---------------- epilogue: tanh * gate + q residual ---------------------
    // C/D mapping: col = lane&15, row = (lane>>4)*4 + reg  [m89/m91]
    #pragma unroll
    for (int m = 0; m < 2; ++m) {
        #pragma unroll
        for (int j = 0; j < 8; ++j) {
            const int col = nw + j * 16 + la;
            const int ckq = 64 + (col >> 3);      // q half: k = 512 + col
            #pragma unroll
            for (int r = 0; r < 4; ++r) {
                const int row = m * 16 + lb * 4 + r;
                float q = __bfloat162float(*(const __hip_bfloat16*)(
                    (const char*)catL + row * 2048 + ((ckq ^ (row & 7)) << 4)
                    + ((col & 7) << 1)));
                float v = fast_tanh(acc[m][j][r]) * gateL[row] + q;
                out[(size_t)(bp + row) * DIM + col] = v;
            }
        }
    }
#undef LOADSTEP
#undef MFMASTEP
}

// ---------------------------------------------------------------------------
extern "C" void kernel_launch(void* const* d_in, const int* in_sizes, int n_in,
                              void* d_out, int out_size, void* d_ws, size_t ws_size,
                              hipStream_t stream) {
    const float* inputs  = (const float*)d_in[0];
    const float* values  = (const float*)d_in[1];
    const float* W_out   = (const float*)d_in[2];
    const float* w_score = (const float*)d_in[3];
    const float* b_score = (const float*)d_in[4];
    const int*   n_ptr   = (const int*)d_in[5];
    float* out = (float*)d_out;

    __hip_bfloat16* Wt = (__hip_bfloat16*)d_ws;   // 1 MiB

    wconv<<<WCONV_BLOCKS, 256, 0, stream>>>(W_out, Wt);
    fused_kernel<<<FUSED_BLOCKS, 256, 0, stream>>>(
        inputs, values, Wt, w_score, b_score, n_ptr, out);
}

// Round 9
// 176.942 us; speedup vs baseline: 1.0693x; 1.0693x over previous
//
#include <hip/hip_runtime.h>
#include <hip/hip_bf16.h>
#include <math.h>

// Problem constants (fixed by setup_inputs)
#define BATCH 8
#define SEQ   4096
#define DIM   512        // D
#define FDIM  4          // F
#define M_TOTAL (BATCH*SEQ)   // 32768 positions
#define K_TOTAL (2*DIM)       // 1024 (cat = [ctx; q])
#define N_TOTAL DIM           // 512

#define MB 32                          // positions per block
#define FUSED_BLOCKS (M_TOTAL/MB)      // 1024
#define WCONV_BLOCKS ((K_TOTAL/64)*(N_TOTAL/64))  // 128 tiles

typedef __bf16 bf16x8 __attribute__((ext_vector_type(8)));
typedef float  f32x4  __attribute__((ext_vector_type(4)));

__device__ __forceinline__ f32x4 ntload(const f32x4* p) {
    return __builtin_nontemporal_load(p);
}

__device__ __forceinline__ float dot4(f32x4 a, f32x4 b) {
    return a.x*b.x + a.y*b.y + a.z*b.z + a.w*b.w;
}

__device__ __forceinline__ void store_bf4(__hip_bfloat16* dst, f32x4 v) {
    __hip_bfloat16 t[4];
    t[0] = __float2bfloat16(v.x); t[1] = __float2bfloat16(v.y);
    t[2] = __float2bfloat16(v.z); t[3] = __float2bfloat16(v.w);
    *reinterpret_cast<uint2*>(dst) = *reinterpret_cast<const uint2*>(t);
}

__device__ __forceinline__ float fast_tanh(float x) {
    float e = __expf(2.f * x);
    return 1.f - 2.f * __builtin_amdgcn_rcpf(e + 1.f);
}

// ---------------------------------------------------------------------------
// Kernel 1: W_out [1024,512] f32 -> Wt [512,1024] bf16 (transpose+convert).
// ---------------------------------------------------------------------------
__global__ __launch_bounds__(256)
void wconv(const float* __restrict__ W, __hip_bfloat16* __restrict__ Wt)
{
    __shared__ float ws[64][65];
    const int tid = threadIdx.x;
    const int t  = blockIdx.x;
    const int k0 = (t & 15) * 64;
    const int n0 = (t >> 4) * 64;
    #pragma unroll
    for (int i = 0; i < 16; ++i) {
        int e = i * 256 + tid;
        int r = e >> 6, c = e & 63;
        ws[r][c] = W[(size_t)(k0 + r) * N_TOTAL + n0 + c];
    }
    __syncthreads();
    #pragma unroll
    for (int i = 0; i < 16; ++i) {
        int e = i * 256 + tid;
        int nr = e >> 6, kc = e & 63;
        Wt[(size_t)(n0 + nr) * K_TOTAL + k0 + kc] = __float2bfloat16(ws[kc][nr]);
    }
}

// ---------------------------------------------------------------------------
// cat LDS layout: [MB rows][1024 K] bf16, rows of 2048 B = 128 chunks of 16 B.
// Chunk ck stored at physical chunk (ck ^ (row&7)) — XOR swizzle so MFMA
// A-frag reads (16 rows, same ck) spread across banks (2-way = free).
// ---------------------------------------------------------------------------
__device__ __forceinline__ void cat_store4(__hip_bfloat16* catL, int row, int k, f32x4 v) {
    int ck   = k >> 3;
    int phys = ck ^ (row & 7);
    char* dst = (char*)catL + row * 2048 + (phys << 4) + ((k & 7) << 1);
    store_bf4((__hip_bfloat16*)dst, v);
}

// ---------------------------------------------------------------------------
// Kernel 2 (fused): 512 threads = 8 waves, MB=32 positions/block.
//  phase 1: wave-per-position attention (4 pos/wave, 2-deep load pipeline)
//           -> cat=[ctx;q] bf16 in LDS + gate.  Nontemporal input loads.
//  phase 2: GEMM [32,1024]x[1024,512]; A from swizzled LDS, B from L2-hot Wt,
//           64 N-cols per wave, depth-1 software pipeline.
//  epilogue: out = tanh(acc)*gate + q (residual from LDS), nontemporal store.
// LDS 64.1 KiB -> 2 blocks/CU = 16 waves/CU; launch_bounds(512,4) caps 128 VGPR.
// ---------------------------------------------------------------------------
__global__ __launch_bounds__(512, 4)
void fused_kernel(const float* __restrict__ inputs,
                  const float* __restrict__ values,
                  const __hip_bfloat16* __restrict__ Bt,   // Wt [512][1024]
                  const float* __restrict__ w_score,
                  const float* __restrict__ b_score,
                  const int*   __restrict__ n_ptr,
                  float* __restrict__ out)
{
    __shared__ __align__(16) __hip_bfloat16 catL[MB * K_TOTAL];  // 64 KiB
    __shared__ float gateL[MB];

    const int tid  = threadIdx.x;
    const int lane = tid & 63;
    const int wv   = tid >> 6;          // 8 waves
    const int bp   = blockIdx.x * MB;
    const int nv   = *n_ptr;
    const float bs = b_score[0];

    // ---------------- phase 1: attention ------------------------------------
    const f32x4* wg = (const f32x4*)w_score;
    const f32x4 w0 = wg[lane], w1 = wg[lane + 64];

    auto ALOAD = [&](int p, f32x4& qa, f32x4& qb, f32x4* mm) {
        const f32x4* qg = (const f32x4*)(inputs + (size_t)(bp + p) * DIM);
        qa = ntload(qg + lane);
        qb = ntload(qg + lane + 64);
        const f32x4* vg = (const f32x4*)(values + (size_t)(bp + p) * (FDIM*DIM));
        #pragma unroll
        for (int f = 0; f < 4; ++f) {
            mm[f]     = ntload(vg + f * 128 + lane);
            mm[4 + f] = ntload(vg + f * 128 + lane + 64);
        }
    };

    auto ACOMP = [&](int p, f32x4 qa, f32x4 qb, const f32x4* mm) {
        float s[4];
        #pragma unroll
        for (int f = 0; f < 4; ++f) s[f] = dot4(qa, mm[f]) + dot4(qb, mm[4 + f]);
        float g = dot4(qa, w0) + dot4(qb, w1);
        #pragma unroll
        for (int off = 1; off < 64; off <<= 1) {
            s[0] += __shfl_xor(s[0], off, 64);
            s[1] += __shfl_xor(s[1], off, 64);
            s[2] += __shfl_xor(s[2], off, 64);
            s[3] += __shfl_xor(s[3], off, 64);
            g    += __shfl_xor(g,    off, 64);
        }
        #pragma unroll
        for (int f = 0; f < 4; ++f) if (f >= nv) s[f] = -1e9f;
        float mx = fmaxf(fmaxf(s[0], s[1]), fmaxf(s[2], s[3]));
        float e0 = __expf(s[0] - mx), e1 = __expf(s[1] - mx);
        float e2 = __expf(s[2] - mx), e3 = __expf(s[3] - mx);
        float inv = __builtin_amdgcn_rcpf(e0 + e1 + e2 + e3);
        float a0 = e0*inv, a1 = e1*inv, a2 = e2*inv, a3 = e3*inv;

        f32x4 ca = mm[0]*a0 + mm[1]*a1 + mm[2]*a2 + mm[3]*a3;
        f32x4 cb = mm[4]*a0 + mm[5]*a1 + mm[6]*a2 + mm[7]*a3;

        cat_store4(catL, p,        lane * 4, ca);
        cat_store4(catL, p, 256 +  lane * 4, cb);
        cat_store4(catL, p, 512 +  lane * 4, qa);
        cat_store4(catL, p, 768 +  lane * 4, qb);
        if (lane == 0) gateL[p] = __builtin_amdgcn_rcpf(1.f + __expf(-(g + bs)));
    };

    {
        const int p0 = wv * 4;
        f32x4 qaA, qbA, mA[8], qaB, qbB, mB_[8];
        ALOAD(p0 + 0, qaA, qbA, mA);
        ALOAD(p0 + 1, qaB, qbB, mB_);
        ACOMP(p0 + 0, qaA, qbA, mA);
        ALOAD(p0 + 2, qaA, qbA, mA);
        ACOMP(p0 + 1, qaB, qbB, mB_);
        ALOAD(p0 + 3, qaB, qbB, mB_);
        ACOMP(p0 + 2, qaA, qbA, mA);
        ACOMP(p0 + 3, qaB, qbB, mB_);
    }

    // ---------------- phase 2: GEMM ------------------------------------------
    const int la = lane & 15;
    const int lb = lane >> 4;
    const int nw = wv * 64;             // wave's 64-col N-chunk

    f32x4 acc[2][4] = {};
    bf16x8 aA[2], bA[4], aB[2], bB[4];

#define LOADB(bf, S) do {                                                     \
        _Pragma("unroll")                                                     \
        for (int j = 0; j < 4; ++j) {                                         \
            int nrow = nw + j * 16 + la;                                      \
            bf[j] = *reinterpret_cast<const bf16x8*>(                         \
                Bt + (size_t)nrow * K_TOTAL + (S) * 32 + lb * 8);             \
        }                                                                     \
    } while (0)

#define LOADA(af, S) do {                                                     \
        int ck0 = (S) * 4 + lb;                                               \
        _Pragma("unroll")                                                     \
        for (int m = 0; m < 2; ++m) {                                         \
            int row = m * 16 + la;                                            \
            af[m] = *reinterpret_cast<const bf16x8*>(                         \
                (const char*)catL + row * 2048 + ((ck0 ^ (row & 7)) << 4));   \
        }                                                                     \
    } while (0)

#define MFMASTEP(af, bf) do {                                                 \
        _Pragma("unroll")                                                     \
        for (int m = 0; m < 2; ++m)                                           \
            _Pragma("unroll")                                                 \
            for (int j = 0; j < 4; ++j)                                       \
                acc[m][j] = __builtin_amdgcn_mfma_f32_16x16x32_bf16(          \
                    af[m], bf[j], acc[m][j], 0, 0, 0);                        \
    } while (0)

    LOADB(bA, 0);          // B prefetch flies while waves drain into barrier
    __syncthreads();
    LOADA(aA, 0);

    #pragma unroll
    for (int s = 0; s < 31; ++s) {
        if ((s & 1) == 0) { LOADB(bB, s + 1); LOADA(aB, s + 1); MFMASTEP(aA, bA); }
        else              { LOADB(bA, s + 1); LOADA(aA, s + 1); MFMASTEP(aB, bB); }
    }
    MFMASTEP(aB, bB);      // step 31 (loaded when s==30)

    // ---------------- epilogue ------------------------------------------------
    // C/D mapping: col = lane&15, row = (lane>>4)*4 + reg  [m89/m91]
    #pragma unroll
    for (int m = 0; m < 2; ++m) {
        #pragma unroll
        for (int j = 0; j < 4; ++j) {
            const int col = nw + j * 16 + la;
            const int ckq = 64 + (col >> 3);      // q half: k = 512 + col
            #pragma unroll
            for (int r = 0; r < 4; ++r) {
                const int row = m * 16 + lb * 4 + r;
                float q = __bfloat162float(*(const __hip_bfloat16*)(
                    (const char*)catL + row * 2048 + ((ckq ^ (row & 7)) << 4)
                    + ((col & 7) << 1)));
                float v = fast_tanh(acc[m][j][r]) * gateL[row] + q;
                __builtin_nontemporal_store(v, &out[(size_t)(bp + row) * DIM + col]);
            }
        }
    }
#undef LOADB
#undef LOADA
#undef MFMASTEP
}

// ---------------------------------------------------------------------------
extern "C" void kernel_launch(void* const* d_in, const int* in_sizes, int n_in,
                              void* d_out, int out_size, void* d_ws, size_t ws_size,
                              hipStream_t stream) {
    const float* inputs  = (const float*)d_in[0];
    const float* values  = (const float*)d_in[1];
    const float* W_out   = (const float*)d_in[2];
    const float* w_score = (const float*)d_in[3];
    const float* b_score = (const float*)d_in[4];
    const int*   n_ptr   = (const int*)d_in[5];
    float* out = (float*)d_out;

    __hip_bfloat16* Wt = (__hip_bfloat16*)d_ws;   // 1 MiB

    wconv<<<WCONV_BLOCKS, 256, 0, stream>>>(W_out, Wt);
    fused_kernel<<<FUSED_BLOCKS, 512, 0, stream>>>(
        inputs, values, Wt, w_score, b_score, n_ptr, out);
}

// Round 10
// 135.248 us; speedup vs baseline: 1.3989x; 1.3083x over previous
//
#include <hip/hip_runtime.h>
#include <hip/hip_bf16.h>
#include <math.h>

// Problem constants (fixed by setup_inputs)
#define BATCH 8
#define SEQ   4096
#define DIM   512        // D
#define FDIM  4          // F
#define M_TOTAL (BATCH*SEQ)   // 32768 positions
#define K_TOTAL (2*DIM)       // 1024 (cat = [ctx; q])
#define N_TOTAL DIM           // 512

#define WCONV_BLOCKS ((K_TOTAL/64)*(N_TOTAL/64))  // 128 tiles, run FIRST
#define PRE_BLOCKS (M_TOTAL/4)                    // 8192 blocks, 4 pos each

// GEMM tile geometry: 128x128, BK=64, 4 waves (2x2), m97 structure
#define BM 128
#define BN 128
#define BK 64
#define GEMM_BLOCKS ((M_TOTAL/BM)*(N_TOTAL/BN))   // 1024

typedef __bf16 bf16x8 __attribute__((ext_vector_type(8)));
typedef float  f32x4  __attribute__((ext_vector_type(4)));

__device__ __forceinline__ void gload_lds16(const void* g, void* l) {
    __builtin_amdgcn_global_load_lds(
        (__attribute__((address_space(1))) void*)(void*)g,
        (__attribute__((address_space(3))) void*)l,
        16, 0, 0);
}

__device__ __forceinline__ f32x4 ntload4(const f32x4* p) {
    return __builtin_nontemporal_load(p);
}

__device__ __forceinline__ float dot4(f32x4 a, f32x4 b) {
    return a.x*b.x + a.y*b.y + a.z*b.z + a.w*b.w;
}

__device__ __forceinline__ void store_bf4(__hip_bfloat16* dst, f32x4 v) {
    __hip_bfloat16 t[4];
    t[0] = __float2bfloat16(v.x); t[1] = __float2bfloat16(v.y);
    t[2] = __float2bfloat16(v.z); t[3] = __float2bfloat16(v.w);
    *reinterpret_cast<uint2*>(dst) = *reinterpret_cast<const uint2*>(t);
}

__device__ __forceinline__ float fast_tanh(float x) {
    float e = __expf(2.f * x);
    return 1.f - 2.f * __builtin_amdgcn_rcpf(e + 1.f);
}

// ---------------------------------------------------------------------------
// Kernel 1 (fused): blocks [0, WCONV_BLOCKS): W_out transpose->bf16 (FIRST,
//                   so it finishes during pre ramp-up — no serial tail)
//                   blocks [WCONV_BLOCKS, +PRE_BLOCKS): wave-per-position attn
// Writes ctx bf16 [M,512] + gate f32 [M].  values loads are NONTEMPORAL
// (never re-read); inputs loads are normal so the 64 MiB input stays L3-hot
// for the gemm's q staging + residual.
// ---------------------------------------------------------------------------
__global__ __launch_bounds__(256)
void pre_kernel(const float* __restrict__ inputs,
                const float* __restrict__ values,
                const float* __restrict__ W,
                const float* __restrict__ w_score,
                const float* __restrict__ b_score,
                const int*   __restrict__ n_ptr,
                __hip_bfloat16* __restrict__ ctx,
                float* __restrict__ gate,
                __hip_bfloat16* __restrict__ Wt)
{
    __shared__ float ws[64][65];   // only used by the wconv path

    const int tid = threadIdx.x;

    if (blockIdx.x < WCONV_BLOCKS) {
        // ---- W_out [1024,512] f32 -> Wt [512,1024] bf16, 64x64 LDS tile ----
        const int t  = blockIdx.x;
        const int k0 = (t & 15) * 64;
        const int n0 = (t >> 4) * 64;
        #pragma unroll
        for (int i = 0; i < 16; ++i) {
            int e = i * 256 + tid;
            int r = e >> 6, c = e & 63;
            ws[r][c] = W[(size_t)(k0 + r) * N_TOTAL + n0 + c];
        }
        __syncthreads();
        #pragma unroll
        for (int i = 0; i < 16; ++i) {
            int e = i * 256 + tid;
            int nr = e >> 6, kc = e & 63;
            Wt[(size_t)(n0 + nr) * K_TOTAL + k0 + kc] = __float2bfloat16(ws[kc][nr]);
        }
        return;
    }

    // ---- wave-per-position attention: no LDS, no barriers ----
    const int lane = tid & 63;
    const int wv   = tid >> 6;
    const int p    = (blockIdx.x - WCONV_BLOCKS) * 4 + wv;

    const f32x4* qg = (const f32x4*)(inputs + (size_t)p * DIM);
    f32x4 qa = qg[lane], qb = qg[lane + 64];

    const f32x4* vg = (const f32x4*)(values + (size_t)p * (FDIM*DIM));
    f32x4 ma[4], mb[4];
    float s[4];
    #pragma unroll
    for (int f = 0; f < 4; ++f) {
        ma[f] = ntload4(vg + f * 128 + lane);
        mb[f] = ntload4(vg + f * 128 + lane + 64);
        s[f] = dot4(qa, ma[f]) + dot4(qb, mb[f]);
    }
    const f32x4* wg = (const f32x4*)w_score;
    float g = dot4(qa, wg[lane]) + dot4(qb, wg[lane + 64]);

    #pragma unroll
    for (int off = 1; off < 64; off <<= 1) {
        s[0] += __shfl_xor(s[0], off, 64);
        s[1] += __shfl_xor(s[1], off, 64);
        s[2] += __shfl_xor(s[2], off, 64);
        s[3] += __shfl_xor(s[3], off, 64);
        g    += __shfl_xor(g,    off, 64);
    }

    const int nv = *n_ptr;
    #pragma unroll
    for (int f = 0; f < 4; ++f) if (f >= nv) s[f] = -1e9f;
    float mx = fmaxf(fmaxf(s[0], s[1]), fmaxf(s[2], s[3]));
    float e0 = __expf(s[0] - mx), e1 = __expf(s[1] - mx);
    float e2 = __expf(s[2] - mx), e3 = __expf(s[3] - mx);
    float inv = __builtin_amdgcn_rcpf(e0 + e1 + e2 + e3);
    float a0 = e0*inv, a1 = e1*inv, a2 = e2*inv, a3 = e3*inv;

    f32x4 ca = ma[0]*a0 + ma[1]*a1 + ma[2]*a2 + ma[3]*a3;
    f32x4 cb = mb[0]*a0 + mb[1]*a1 + mb[2]*a2 + mb[3]*a3;

    __hip_bfloat16* cp = ctx + (size_t)p * DIM;
    store_bf4(cp +       4 * lane, ca);
    store_bf4(cp + 256 + 4 * lane, cb);

    if (lane == 0) {
        gate[p] = __builtin_amdgcn_rcpf(1.f + __expf(-(g + b_score[0])));
    }
}

// ---------------------------------------------------------------------------
// Kernel 2: out = tanh([ctx; q] @ W_out) * gate + q
// m97 structure: 128x128 tile, BK=64, 4 waves (2x2), 4x4 frags/wave,
// single-buffer 2-barrier K-loop, XOR source-swizzle == read swizzle.
// K-split: kt<512 -> A from ctx bf16 (global_load_lds);
//          kt>=512 -> A reg-staged from inputs f32 (L3-hot), 2-pass batches.
// Natural block order (4 consecutive blocks share an A-panel -> L3 temporal).
// Nontemporal out stores (never re-read) keep L2/L3 for inputs/Wt.
// ---------------------------------------------------------------------------
__global__ __launch_bounds__(256, 4)
void gemm_ep(const __hip_bfloat16* __restrict__ Actx,  // ctx [M,512]
             const __hip_bfloat16* __restrict__ Bt,    // Wt  [512,1024]
             const float* __restrict__ gate,
             const float* __restrict__ inputs,
             float* __restrict__ out)
{
    __shared__ __align__(16) __hip_bfloat16 As[BM * BK];  // 16 KB
    __shared__ __align__(16) __hip_bfloat16 Bs[BN * BK];  // 16 KB
    __shared__ float gateLds[BM];

    const int tid = threadIdx.x;
    const int bm = blockIdx.x >> 2;     // 0..255
    const int bn = blockIdx.x & 3;      // 0..3

    const int wid  = tid >> 6;
    const int lane = tid & 63;
    const int wr   = wid >> 1;
    const int wc   = wid & 1;
    const int la   = lane & 15;
    const int lb   = lane >> 4;

    const __hip_bfloat16* Ag = Actx + (size_t)(bm * BM) * DIM;    // stride 512
    const float*          Qg = inputs + (size_t)(bm * BM) * DIM;  // stride 512
    const __hip_bfloat16* Bg = Bt + (size_t)(bn * BN) * K_TOTAL;  // stride 1024

    if (tid < BM) gateLds[tid] = gate[bm * BM + tid];

    f32x4 acc[4][4] = {};

    for (int kt = 0; kt < K_TOTAL; kt += BK) {
        __syncthreads();
        if (kt < 512) {
            #pragma unroll
            for (int ps = 0; ps < 4; ++ps) {
                int cl  = ps * 256 + tid;
                int row = cl >> 3;
                int c   = cl & 7;
                int sc_ = c ^ (row & 7);
                gload_lds16(Ag + (size_t)row * DIM + kt + sc_ * 8, As + cl * 8);
                gload_lds16(Bg + (size_t)row * K_TOTAL + kt + sc_ * 8, Bs + cl * 8);
            }
        } else {
            #pragma unroll
            for (int ps = 0; ps < 4; ++ps) {
                int cl  = ps * 256 + tid;
                int row = cl >> 3;
                int c   = cl & 7;
                int sc_ = c ^ (row & 7);
                gload_lds16(Bg + (size_t)row * K_TOTAL + kt + sc_ * 8, Bs + cl * 8);
            }
            // A q-half: f32 (L3-hot) -> bf16, 2 passes per batch (reg-lean)
            #pragma unroll
            for (int bt = 0; bt < 2; ++bt) {
                f32x4 f[4];
                int cls[2];
                #pragma unroll
                for (int ps = 0; ps < 2; ++ps) {
                    int cl  = (bt * 2 + ps) * 256 + tid;
                    int row = cl >> 3;
                    int c   = cl & 7;
                    int sc_ = c ^ (row & 7);
                    const f32x4* src = (const f32x4*)(Qg + (size_t)row * DIM
                                                      + (kt - 512) + sc_ * 8);
                    f[ps*2]   = src[0];
                    f[ps*2+1] = src[1];
                    cls[ps] = cl;
                }
                #pragma unroll
                for (int ps = 0; ps < 2; ++ps) {
                    __hip_bfloat16 t[8];
                    t[0] = __float2bfloat16(f[ps*2].x);   t[1] = __float2bfloat16(f[ps*2].y);
                    t[2] = __float2bfloat16(f[ps*2].z);   t[3] = __float2bfloat16(f[ps*2].w);
                    t[4] = __float2bfloat16(f[ps*2+1].x); t[5] = __float2bfloat16(f[ps*2+1].y);
                    t[6] = __float2bfloat16(f[ps*2+1].z); t[7] = __float2bfloat16(f[ps*2+1].w);
                    *reinterpret_cast<uint4*>(As + cls[ps] * 8) =
                        *reinterpret_cast<const uint4*>(t);
                }
            }
        }
        __syncthreads();

        #pragma unroll
        for (int kk = 0; kk < 2; ++kk) {
            bf16x8 af[4], bfv[4];
            #pragma unroll
            for (int i = 0; i < 4; ++i) {
                int row = wr * 64 + i * 16 + la;
                int cc  = (kk * 4 + lb) ^ (row & 7);
                af[i] = *reinterpret_cast<const bf16x8*>(As + row * BK + cc * 8);
            }
            #pragma unroll
            for (int j = 0; j < 4; ++j) {
                int row = wc * 64 + j * 16 + la;
                int cc  = (kk * 4 + lb) ^ (row & 7);
                bfv[j] = *reinterpret_cast<const bf16x8*>(Bs + row * BK + cc * 8);
            }
            #pragma unroll
            for (int i = 0; i < 4; ++i)
                #pragma unroll
                for (int j = 0; j < 4; ++j)
                    acc[i][j] = __builtin_amdgcn_mfma_f32_16x16x32_bf16(af[i], bfv[j], acc[i][j], 0, 0, 0);
        }
    }

    // Epilogue: C/D mapping col = lane&15, row = (lane>>4)*4 + reg  [m89/m91]
    const int row0 = bm * BM + wr * 64;
    const int col0 = bn * BN + wc * 64;
    #pragma unroll
    for (int i = 0; i < 4; ++i) {
        #pragma unroll
        for (int j = 0; j < 4; ++j) {
            const int col = col0 + j * 16 + la;
            const int rb  = row0 + i * 16 + lb * 4;
            #pragma unroll
            for (int r = 0; r < 4; ++r) {
                const int row = rb + r;
                float q = inputs[(size_t)row * DIM + col];   // L3-hot
                float v = fast_tanh(acc[i][j][r]) * gateLds[row - bm * BM] + q;
                __builtin_nontemporal_store(v, &out[(size_t)row * DIM + col]);
            }
        }
    }
}

// ---------------------------------------------------------------------------
extern "C" void kernel_launch(void* const* d_in, const int* in_sizes, int n_in,
                              void* d_out, int out_size, void* d_ws, size_t ws_size,
                              hipStream_t stream) {
    const float* inputs  = (const float*)d_in[0];
    const float* values  = (const float*)d_in[1];
    const float* W_out   = (const float*)d_in[2];
    const float* w_score = (const float*)d_in[3];
    const float* b_score = (const float*)d_in[4];
    const int*   n_ptr   = (const int*)d_in[5];
    float* out = (float*)d_out;

    char* ws = (char*)d_ws;
    __hip_bfloat16* ctx  = (__hip_bfloat16*)ws;                                   // 32 MiB
    float*          gate = (float*)(ws + (size_t)M_TOTAL * DIM * 2);              // 128 KiB
    __hip_bfloat16* Wt   = (__hip_bfloat16*)(ws + (size_t)M_TOTAL * DIM * 2
                                                + (size_t)M_TOTAL * 4);           // 1 MiB

    pre_kernel<<<WCONV_BLOCKS + PRE_BLOCKS, 256, 0, stream>>>(
        inputs, values, W_out, w_score, b_score, n_ptr, ctx, gate, Wt);
    gemm_ep<<<GEMM_BLOCKS, 256, 0, stream>>>(ctx, Wt, gate, inputs, out);
}

// Round 11
// 127.462 us; speedup vs baseline: 1.4843x; 1.0611x over previous
//
#include <hip/hip_runtime.h>
#include <hip/hip_bf16.h>
#include <math.h>

// Problem constants (fixed by setup_inputs)
#define BATCH 8
#define SEQ   4096
#define DIM   512        // D
#define FDIM  4          // F
#define M_TOTAL (BATCH*SEQ)   // 32768 positions
#define K_TOTAL (2*DIM)       // 1024 (cat = [ctx; q])
#define N_TOTAL DIM           // 512

#define WCONV_BLOCKS ((K_TOTAL/64)*(N_TOTAL/64))  // 128 tiles, run FIRST
#define PRE_BLOCKS (M_TOTAL/4)                    // 8192 blocks, 4 pos each

typedef __bf16 bf16x8 __attribute__((ext_vector_type(8)));
typedef float  f32x4  __attribute__((ext_vector_type(4)));

__device__ __forceinline__ void gload_lds16(const void* g, void* l) {
    __builtin_amdgcn_global_load_lds(
        (__attribute__((address_space(1))) void*)(void*)g,
        (__attribute__((address_space(3))) void*)l,
        16, 0, 0);
}

__device__ __forceinline__ float dot4(float4 a, float4 b) {
    return a.x*b.x + a.y*b.y + a.z*b.z + a.w*b.w;
}

__device__ __forceinline__ void store_bf4(__hip_bfloat16* dst, float4 v) {
    __hip_bfloat16 t[4];
    t[0] = __float2bfloat16(v.x); t[1] = __float2bfloat16(v.y);
    t[2] = __float2bfloat16(v.z); t[3] = __float2bfloat16(v.w);
    *reinterpret_cast<uint2*>(dst) = *reinterpret_cast<const uint2*>(t);
}

__device__ __forceinline__ float fast_tanh(float x) {
    // tanh(x) = 1 - 2/(e^{2x}+1); saturates correctly for |x| large (inf -> 1)
    float e = __expf(2.f * x);
    return 1.f - 2.f * __builtin_amdgcn_rcpf(e + 1.f);
}

// ---------------------------------------------------------------------------
// Kernel 1 (fused): blocks [0, WCONV_BLOCKS): W_out transpose->bf16 (FIRST so
//                   it finishes during pre ramp-up — no serial tail)
//                   blocks [WCONV_BLOCKS, +PRE_BLOCKS): wave-per-position attn
// Writes ONLY ctx (bf16, [M,512]) — the q half of cat is staged by the GEMM
// directly from inputs.
// ---------------------------------------------------------------------------
__global__ __launch_bounds__(256)
void pre_kernel(const float* __restrict__ inputs,
                const float* __restrict__ values,
                const float* __restrict__ W,
                const float* __restrict__ w_score,
                const float* __restrict__ b_score,
                const int*   __restrict__ n_ptr,
                __hip_bfloat16* __restrict__ ctx,
                float* __restrict__ gate,
                __hip_bfloat16* __restrict__ Wt)
{
    __shared__ float ws[64][65];   // only used by the wconv path (16.6 KB)

    const int tid  = threadIdx.x;

    if (blockIdx.x < WCONV_BLOCKS) {
        // ---- W_out [1024,512] f32 -> Wt [512,1024] bf16, 64x64 LDS tile ----
        const int t  = blockIdx.x;
        const int k0 = (t & 15) * 64;     // row tile in W (K dim)
        const int n0 = (t >> 4) * 64;     // col tile in W (N dim)
        #pragma unroll
        for (int i = 0; i < 16; ++i) {
            int e = i * 256 + tid;
            int r = e >> 6, c = e & 63;
            ws[r][c] = W[(size_t)(k0 + r) * N_TOTAL + n0 + c];
        }
        __syncthreads();
        #pragma unroll
        for (int i = 0; i < 16; ++i) {
            int e = i * 256 + tid;
            int nr = e >> 6, kc = e & 63;
            Wt[(size_t)(n0 + nr) * K_TOTAL + k0 + kc] = __float2bfloat16(ws[kc][nr]);
        }
        return;
    }

    // ---- wave-per-position attention: no LDS, no barriers ----
    const int lane = tid & 63;
    const int wv   = tid >> 6;
    const int p    = (blockIdx.x - WCONV_BLOCKS) * 4 + wv;

    const float4* qg = (const float4*)(inputs + (size_t)p * DIM);
    float4 qa = qg[lane], qb = qg[lane + 64];

    const float4* vg = (const float4*)(values + (size_t)p * (FDIM*DIM));
    float4 ma[4], mb[4];
    float s[4];
    #pragma unroll
    for (int f = 0; f < 4; ++f) {
        ma[f] = vg[f * 128 + lane];
        mb[f] = vg[f * 128 + lane + 64];
        s[f] = dot4(qa, ma[f]) + dot4(qb, mb[f]);
    }
    const float4* wg = (const float4*)w_score;
    float g = dot4(qa, wg[lane]) + dot4(qb, wg[lane + 64]);

    // butterfly reduce the 4 scores + gate across the wave
    #pragma unroll
    for (int off = 1; off < 64; off <<= 1) {
        s[0] += __shfl_xor(s[0], off, 64);
        s[1] += __shfl_xor(s[1], off, 64);
        s[2] += __shfl_xor(s[2], off, 64);
        s[3] += __shfl_xor(s[3], off, 64);
        g    += __shfl_xor(g,    off, 64);
    }

    const int nv = *n_ptr;
    #pragma unroll
    for (int f = 0; f < 4; ++f) if (f >= nv) s[f] = -1e9f;
    float mx = fmaxf(fmaxf(s[0], s[1]), fmaxf(s[2], s[3]));
    float e0 = __expf(s[0] - mx), e1 = __expf(s[1] - mx);
    float e2 = __expf(s[2] - mx), e3 = __expf(s[3] - mx);
    float inv = __builtin_amdgcn_rcpf(e0 + e1 + e2 + e3);
    float a[4] = { e0 * inv, e1 * inv, e2 * inv, e3 * inv };

    float4 ca = {0.f, 0.f, 0.f, 0.f}, cb = {0.f, 0.f, 0.f, 0.f};
    #pragma unroll
    for (int f = 0; f < 4; ++f) {
        ca.x += a[f] * ma[f].x; ca.y += a[f] * ma[f].y;
        ca.z += a[f] * ma[f].z; ca.w += a[f] * ma[f].w;
        cb.x += a[f] * mb[f].x; cb.y += a[f] * mb[f].y;
        cb.z += a[f] * mb[f].z; cb.w += a[f] * mb[f].w;
    }

    __hip_bfloat16* cp = ctx + (size_t)p * DIM;
    store_bf4(cp +        4 * lane, ca);
    store_bf4(cp + 256  + 4 * lane, cb);

    if (lane == 0) {
        float t = g + b_score[0];
        gate[p] = __builtin_amdgcn_rcpf(1.f + __expf(-t));
    }
}

// ---------------------------------------------------------------------------
// Kernel 2: out = tanh([ctx; q] @ W_out) * gate + inputs
// bf16 MFMA GEMM, BM=BN=128, BK=64, 4 waves (2x2), 4x4 16x16 frags per wave.
// K-split: kt<512 -> A from ctx bf16 (global_load_lds, swizzled source);
//          kt>=512 -> A reg-staged from inputs f32 (cvt->ds_write, swizzled src).
// Bt = Wt [N,1024] row-major bf16 (B^T), always global_load_lds.
// __launch_bounds__(256,4): cap 128 VGPR -> 4 blocks/CU -> grid of 1024 runs
// in exactly one residency round (no tail).
// Grid dim3(256,4): x (bm) fastest -> consecutive dispatches share the B-panel
// (L2-resident); A panels re-read across the 4 bn sweeps via L3.
// ---------------------------------------------------------------------------
__global__ __launch_bounds__(256, 4)
void gemm_ep(const __hip_bfloat16* __restrict__ Actx,
             const __hip_bfloat16* __restrict__ Bt,
             const float* __restrict__ gate,
             const float* __restrict__ inputs,
             float* __restrict__ out)
{
    __shared__ __align__(16) __hip_bfloat16 As[128 * 64];  // 16 KB
    __shared__ __align__(16) __hip_bfloat16 Bs[128 * 64];  // 16 KB

    const int tid  = threadIdx.x;
    const int bm   = blockIdx.x;
    const int bn   = blockIdx.y;
    const int wid  = tid >> 6;
    const int lane = tid & 63;
    const int wr   = wid >> 1;       // wave row 0..1
    const int wc   = wid & 1;        // wave col 0..1
    const int la   = lane & 15;
    const int lb   = lane >> 4;

    const __hip_bfloat16* Ag = Actx + (size_t)(bm * 128) * DIM;       // stride 512
    const float*          Qg = inputs + (size_t)(bm * 128) * DIM;     // stride 512
    const __hip_bfloat16* Bg = Bt + (size_t)(bn * 128) * K_TOTAL;     // stride 1024

    f32x4 acc[4][4] = {};

    for (int kt = 0; kt < K_TOTAL; kt += 64) {
        __syncthreads();
        // stage 128x64 of A and B: 4 passes x 256 threads x 16B each.
        // LDS dest linear; source chunk XOR'd with (row&7) (matches read).
        if (kt < 512) {
            #pragma unroll
            for (int ps = 0; ps < 4; ++ps) {
                int cl  = ps * 256 + tid;        // linear 16B-chunk index
                int row = cl >> 3;               // 8 chunks per 64-elem row
                int c   = cl & 7;
                int sc_ = c ^ (row & 7);
                gload_lds16(Ag + (size_t)row * DIM + kt + sc_ * 8, As + cl * 8);
                gload_lds16(Bg + (size_t)row * K_TOTAL + kt + sc_ * 8, Bs + cl * 8);
            }
        } else {
            #pragma unroll
            for (int ps = 0; ps < 4; ++ps) {
                int cl  = ps * 256 + tid;
                int row = cl >> 3;
                int c   = cl & 7;
                int sc_ = c ^ (row & 7);
                gload_lds16(Bg + (size_t)row * K_TOTAL + kt + sc_ * 8, Bs + cl * 8);
                // A q-half: f32 -> bf16 reg-staged
                const float* src = Qg + (size_t)row * DIM + (kt - 512) + sc_ * 8;
                float4 f0 = ((const float4*)src)[0];
                float4 f1 = ((const float4*)src)[1];
                __hip_bfloat16 t[8];
                t[0] = __float2bfloat16(f0.x); t[1] = __float2bfloat16(f0.y);
                t[2] = __float2bfloat16(f0.z); t[3] = __float2bfloat16(f0.w);
                t[4] = __float2bfloat16(f1.x); t[5] = __float2bfloat16(f1.y);
                t[6] = __float2bfloat16(f1.z); t[7] = __float2bfloat16(f1.w);
                *reinterpret_cast<uint4*>(As + cl * 8) = *reinterpret_cast<const uint4*>(t);
            }
        }
        __syncthreads();   // compiler emits vmcnt/lgkm drain before barrier

        #pragma unroll
        for (int kk = 0; kk < 2; ++kk) {
            bf16x8 af[4], bfv[4];
            #pragma unroll
            for (int i = 0; i < 4; ++i) {
                int row = wr * 64 + i * 16 + la;
                int c   = (kk * 4 + lb) ^ (row & 7);
                af[i] = *reinterpret_cast<const bf16x8*>(As + row * 64 + c * 8);
            }
            #pragma unroll
            for (int j = 0; j < 4; ++j) {
                int row = wc * 64 + j * 16 + la;
                int c   = (kk * 4 + lb) ^ (row & 7);
                bfv[j] = *reinterpret_cast<const bf16x8*>(Bs + row * 64 + c * 8);
            }
            #pragma unroll
            for (int i = 0; i < 4; ++i)
                #pragma unroll
                for (int j = 0; j < 4; ++j)
                    acc[i][j] = __builtin_amdgcn_mfma_f32_16x16x32_bf16(af[i], bfv[j], acc[i][j], 0, 0, 0);
        }
    }

    // Epilogue: C/D mapping col = lane&15, row = (lane>>4)*4 + reg  [m89/m91]
    const int row0 = bm * 128 + wr * 64;
    const int col0 = bn * 128 + wc * 64;
    #pragma unroll
    for (int i = 0; i < 4; ++i) {
        #pragma unroll
        for (int j = 0; j < 4; ++j) {
            const int col = col0 + j * 16 + la;
            const int rb  = row0 + i * 16 + lb * 4;
            #pragma unroll
            for (int r = 0; r < 4; ++r) {
                const int row = rb + r;
                float v = fast_tanh(acc[i][j][r]) * gate[row] + inputs[(size_t)row * DIM + col];
                out[(size_t)row * DIM + col] = v;
            }
        }
    }
}

// ---------------------------------------------------------------------------
extern "C" void kernel_launch(void* const* d_in, const int* in_sizes, int n_in,
                              void* d_out, int out_size, void* d_ws, size_t ws_size,
                              hipStream_t stream) {
    const float* inputs  = (const float*)d_in[0];
    const float* values  = (const float*)d_in[1];
    const float* W_out   = (const float*)d_in[2];
    const float* w_score = (const float*)d_in[3];
    const float* b_score = (const float*)d_in[4];
    const int*   n_ptr   = (const int*)d_in[5];
    float* out = (float*)d_out;

    char* ws = (char*)d_ws;
    __hip_bfloat16* ctx  = (__hip_bfloat16*)ws;                                   // 32 MiB
    float*          gate = (float*)(ws + (size_t)M_TOTAL * DIM * 2);              // 128 KiB
    __hip_bfloat16* Wt   = (__hip_bfloat16*)(ws + (size_t)M_TOTAL * DIM * 2
                                                + (size_t)M_TOTAL * 4);           // 1 MiB

    pre_kernel<<<WCONV_BLOCKS + PRE_BLOCKS, 256, 0, stream>>>(
        inputs, values, W_out, w_score, b_score, n_ptr, ctx, gate, Wt);
    dim3 g3(M_TOTAL / 128, N_TOTAL / 128);
    gemm_ep<<<g3, 256, 0, stream>>>(ctx, Wt, gate, inputs, out);
}